// Round 1
// baseline (1076.109 us; speedup 1.0000x reference)
//
#include <hip/hip_runtime.h>

// Problem constants (B=16,H=32,W=32,D=256,K=8192)
constexpr int NROWS = 16384;   // B*H*W
constexpr int D     = 256;
constexpr int K     = 8192;

constexpr float DECAY = 0.99f;
constexpr float OMD   = 0.01f;   // 1 - DECAY
constexpr float EPSF  = 1e-5f;

// Output layout (flat fp32, concatenated in return order)
constexpr size_t OUT_Q    = 0;                          // quantize_st  : NROWS*D
constexpr size_t OUT_LOSS = (size_t)NROWS * D;          // latent_loss  : 1
constexpr size_t OUT_NE   = OUT_LOSS + 1;               // new_embed    : D*K
constexpr size_t OUT_NCS  = OUT_NE + (size_t)D * K;     // new_cluster  : K
constexpr size_t OUT_NEA  = OUT_NCS + K;                // new_embed_avg: D*K

// ---------------------------------------------------------------------------
// K1: init EMA outputs with decay*old  (scatter adds 0.01*contrib later)
__global__ void init_ema_kernel(const float* __restrict__ embed_avg,
                                const float* __restrict__ cluster_size,
                                float* __restrict__ nea_out,
                                float* __restrict__ ncs_out) {
    size_t i = (size_t)blockIdx.x * blockDim.x + threadIdx.x;   // < D*K
    nea_out[i] = DECAY * embed_avg[i];
    if (i < (size_t)K) ncs_out[i] = DECAY * cluster_size[i];
}

// K1b: sum(cluster_size) -> ws.nsum  (n = 0.99*sum + 0.01*NROWS, assignment-free)
__global__ void cs_sum_kernel(const float* __restrict__ cluster_size,
                              float* __restrict__ nsum) {
    int i = blockIdx.x * blockDim.x + threadIdx.x;   // 8192 threads
    float v = cluster_size[i];
    #pragma unroll
    for (int off = 32; off > 0; off >>= 1) v += __shfl_down(v, off);
    __shared__ float wsum[4];
    if ((threadIdx.x & 63) == 0) wsum[threadIdx.x >> 6] = v;
    __syncthreads();
    if (threadIdx.x == 0)
        atomicAdd(nsum, wsum[0] + wsum[1] + wsum[2] + wsum[3]);
}

// K2: enorm[k] = sum_d embed[d,k]^2
__global__ void enorm_kernel(const float* __restrict__ embed,
                             float* __restrict__ enorm) {
    int k = blockIdx.x * blockDim.x + threadIdx.x;   // 8192 threads
    float a0 = 0.f, a1 = 0.f, a2 = 0.f, a3 = 0.f;
    for (int d = 0; d < D; d += 4) {
        float e0 = embed[(size_t)(d + 0) * K + k];
        float e1 = embed[(size_t)(d + 1) * K + k];
        float e2 = embed[(size_t)(d + 2) * K + k];
        float e3 = embed[(size_t)(d + 3) * K + k];
        a0 = fmaf(e0, e0, a0); a1 = fmaf(e1, e1, a1);
        a2 = fmaf(e2, e2, a2); a3 = fmaf(e3, e3, a3);
    }
    enorm[k] = (a0 + a1) + (a2 + a3);
}

// ---------------------------------------------------------------------------
// K3: the big one. 128x128 tile of score matrix, fp32, 8x8 per thread.
// score(r,k) = enorm[k] - 2*dot(x_r, e_k)   (||x_r||^2 omitted: row-constant)
// Per-row argmin merged across col-tiles via atomicMin on packed u64 key:
// key = (sortable_bits(score) << 32) | k   -> min => min score, tie => min k.
__global__ __launch_bounds__(256) void dist_argmin_kernel(
        const float* __restrict__ x, const float* __restrict__ embed,
        const float* __restrict__ enorm,
        unsigned long long* __restrict__ keys) {
    __shared__ float xs[16][136];   // [dd][row]  (transposed), pad->16B-aligned rows
    __shared__ float es[16][136];   // [dd][col]

    const int tid = threadIdx.x;
    const int tx  = tid & 15;       // col group (8 cols each)
    const int ty  = tid >> 4;       // row group (8 rows each)
    const int colBase = blockIdx.x * 128;
    const int rowBase = blockIdx.y * 128;

    float acc[8][8];
    #pragma unroll
    for (int i = 0; i < 8; ++i)
        #pragma unroll
        for (int j = 0; j < 8; ++j) acc[i][j] = 0.f;

    // staging thread mapping
    const int xc = tid & 3;         // which float4 chunk of the 16-d slice
    const int xi = tid >> 2;        // row 0..63 (and +64)
    const int ej = tid & 31;        // float4 col chunk 0..31
    const int ed = tid >> 5;        // d row 0..7 (and +8)

    for (int dstep = 0; dstep < D; dstep += 16) {
        float4 v0 = *(const float4*)&x[(size_t)(rowBase + xi) * D + dstep + xc * 4];
        float4 v1 = *(const float4*)&x[(size_t)(rowBase + xi + 64) * D + dstep + xc * 4];
        float4 e0 = *(const float4*)&embed[(size_t)(dstep + ed) * K + colBase + ej * 4];
        float4 e1 = *(const float4*)&embed[(size_t)(dstep + ed + 8) * K + colBase + ej * 4];

        xs[xc * 4 + 0][xi] = v0.x;  xs[xc * 4 + 1][xi] = v0.y;
        xs[xc * 4 + 2][xi] = v0.z;  xs[xc * 4 + 3][xi] = v0.w;
        xs[xc * 4 + 0][xi + 64] = v1.x;  xs[xc * 4 + 1][xi + 64] = v1.y;
        xs[xc * 4 + 2][xi + 64] = v1.z;  xs[xc * 4 + 3][xi + 64] = v1.w;
        *(float4*)&es[ed][ej * 4]     = e0;
        *(float4*)&es[ed + 8][ej * 4] = e1;
        __syncthreads();

        #pragma unroll
        for (int dd = 0; dd < 16; ++dd) {
            float4 a0 = *(const float4*)&xs[dd][ty * 8];
            float4 a1 = *(const float4*)&xs[dd][ty * 8 + 4];
            float4 b0 = *(const float4*)&es[dd][tx * 8];
            float4 b1 = *(const float4*)&es[dd][tx * 8 + 4];
            float a[8] = {a0.x, a0.y, a0.z, a0.w, a1.x, a1.y, a1.z, a1.w};
            float b[8] = {b0.x, b0.y, b0.z, b0.w, b1.x, b1.y, b1.z, b1.w};
            #pragma unroll
            for (int i = 0; i < 8; ++i)
                #pragma unroll
                for (int j = 0; j < 8; ++j)
                    acc[i][j] = fmaf(a[i], b[j], acc[i][j]);
        }
        __syncthreads();
    }

    // epilogue: per-thread min over its 8 cols, reduce across tx, atomicMin
    float4 en0 = *(const float4*)&enorm[colBase + tx * 8];
    float4 en1 = *(const float4*)&enorm[colBase + tx * 8 + 4];
    float en[8] = {en0.x, en0.y, en0.z, en0.w, en1.x, en1.y, en1.z, en1.w};

    #pragma unroll
    for (int i = 0; i < 8; ++i) {
        float best = __builtin_inff();
        int bk = colBase + tx * 8;
        #pragma unroll
        for (int j = 0; j < 8; ++j) {
            float s = fmaf(-2.f, acc[i][j], en[j]);
            if (s < best) { best = s; bk = colBase + tx * 8 + j; }
        }
        unsigned int u = __float_as_uint(best);
        u ^= (u >> 31) ? 0xFFFFFFFFu : 0x80000000u;   // monotonic float->uint
        unsigned long long key = ((unsigned long long)u << 32) | (unsigned int)bk;
        #pragma unroll
        for (int m = 1; m < 16; m <<= 1) {
            unsigned long long o = __shfl_xor(key, m);
            key = o < key ? o : key;
        }
        if (tx == 0) atomicMin(&keys[rowBase + ty * 8 + i], key);
    }
}

// ---------------------------------------------------------------------------
// K4: EMA scatter. One block per row; thread d adds 0.01*x[r,d] into col idx.
__global__ void scatter_kernel(const float* __restrict__ x,
                               const unsigned long long* __restrict__ keys,
                               float* __restrict__ nea_out,
                               float* __restrict__ ncs_out) {
    int r = blockIdx.x;
    int d = threadIdx.x;
    unsigned int k = (unsigned int)keys[r];
    atomicAdd(&nea_out[(size_t)d * K + k], OMD * x[(size_t)r * D + d]);
    if (d == 0) atomicAdd(&ncs_out[k], OMD);
}

// K5: quantize gather + latent loss reduction
__global__ void quantize_loss_kernel(const float* __restrict__ x,
                                     const float* __restrict__ embed,
                                     const unsigned long long* __restrict__ keys,
                                     float* __restrict__ q_out,
                                     float* __restrict__ loss_out) {
    float lsum = 0.f;
    const size_t total = (size_t)NROWS * D;
    for (size_t g = (size_t)blockIdx.x * blockDim.x + threadIdx.x; g < total;
         g += (size_t)gridDim.x * blockDim.x) {
        int r = (int)(g >> 8);
        int d = (int)(g & 255);
        unsigned int k = (unsigned int)keys[r];
        float q  = embed[(size_t)d * K + k];
        float xv = x[g];
        q_out[g] = q;
        float diff = q - xv;
        lsum = fmaf(diff, diff, lsum);
    }
    #pragma unroll
    for (int off = 32; off > 0; off >>= 1) lsum += __shfl_down(lsum, off);
    __shared__ float wsum[4];
    if ((threadIdx.x & 63) == 0) wsum[threadIdx.x >> 6] = lsum;
    __syncthreads();
    if (threadIdx.x == 0) {
        float s = wsum[0] + wsum[1] + wsum[2] + wsum[3];
        atomicAdd(loss_out, s * (1.0f / ((float)NROWS * (float)D)));
    }
}

// K6: new_embed = new_embed_avg / cs(k)
__global__ void new_embed_kernel(const float* __restrict__ nea_out,
                                 const float* __restrict__ ncs_out,
                                 const float* __restrict__ nsum,
                                 float* __restrict__ ne_out) {
    size_t i = (size_t)blockIdx.x * blockDim.x + threadIdx.x;   // < D*K
    int k = (int)(i & (size_t)(K - 1));
    float n  = DECAY * (*nsum) + OMD * (float)NROWS;
    float cs = (ncs_out[k] + EPSF) / (n + (float)K * EPSF) * n;
    ne_out[i] = nea_out[i] / cs;
}

// ---------------------------------------------------------------------------
extern "C" void kernel_launch(void* const* d_in, const int* in_sizes, int n_in,
                              void* d_out, int out_size, void* d_ws, size_t ws_size,
                              hipStream_t stream) {
    (void)in_sizes; (void)n_in; (void)out_size; (void)ws_size;
    const float* x            = (const float*)d_in[0];
    const float* embed        = (const float*)d_in[1];
    const float* cluster_size = (const float*)d_in[2];
    const float* embed_avg    = (const float*)d_in[3];
    float* out = (float*)d_out;

    // workspace layout
    unsigned long long* keys = (unsigned long long*)d_ws;                 // NROWS u64
    float* enorm = (float*)((char*)d_ws + (size_t)NROWS * 8);             // K floats
    float* nsum  = (float*)((char*)d_ws + (size_t)NROWS * 8 + (size_t)K * 4); // 1 float

    float* q_out   = out + OUT_Q;
    float* loss_out= out + OUT_LOSS;
    float* ne_out  = out + OUT_NE;
    float* ncs_out = out + OUT_NCS;
    float* nea_out = out + OUT_NEA;

    hipMemsetAsync(keys, 0xFF, (size_t)NROWS * 8, stream);
    hipMemsetAsync(nsum, 0, 4, stream);
    hipMemsetAsync(loss_out, 0, 4, stream);

    init_ema_kernel<<<dim3((D * K) / 256), dim3(256), 0, stream>>>(
        embed_avg, cluster_size, nea_out, ncs_out);
    cs_sum_kernel<<<dim3(K / 256), dim3(256), 0, stream>>>(cluster_size, nsum);
    enorm_kernel<<<dim3(K / 256), dim3(256), 0, stream>>>(embed, enorm);

    dist_argmin_kernel<<<dim3(K / 128, NROWS / 128), dim3(256), 0, stream>>>(
        x, embed, enorm, keys);

    scatter_kernel<<<dim3(NROWS), dim3(256), 0, stream>>>(x, keys, nea_out, ncs_out);
    quantize_loss_kernel<<<dim3(512), dim3(256), 0, stream>>>(
        x, embed, keys, q_out, loss_out);
    new_embed_kernel<<<dim3((D * K) / 256), dim3(256), 0, stream>>>(
        nea_out, ncs_out, nsum, ne_out);
}

// Round 2
// 553.395 us; speedup vs baseline: 1.9446x; 1.9446x over previous
//
#include <hip/hip_runtime.h>

// Problem constants (B=16,H=32,W=32,D=256,K=8192)
constexpr int NROWS = 16384;   // B*H*W
constexpr int D     = 256;
constexpr int K     = 8192;

constexpr float DECAY = 0.99f;
constexpr float OMD   = 0.01f;   // 1 - DECAY
constexpr float EPSF  = 1e-5f;

// Output layout (flat fp32, concatenated in return order)
constexpr size_t OUT_Q    = 0;                          // quantize_st  : NROWS*D
constexpr size_t OUT_LOSS = (size_t)NROWS * D;          // latent_loss  : 1
constexpr size_t OUT_NE   = OUT_LOSS + 1;               // new_embed    : D*K
constexpr size_t OUT_NCS  = OUT_NE + (size_t)D * K;     // new_cluster  : K
constexpr size_t OUT_NEA  = OUT_NCS + K;                // new_embed_avg: D*K

// Workspace byte offsets
constexpr size_t WS_KEYS  = 0;                              // NROWS u64   (128 KB)
constexpr size_t WS_ENORM = WS_KEYS + (size_t)NROWS * 8;    // K f32       (32 KB)
constexpr size_t WS_NSUM  = WS_ENORM + (size_t)K * 4;       // 1 f32
constexpr size_t WS_XH    = ((WS_NSUM + 4096) / 4096) * 4096;       // NROWS*D bf16
constexpr size_t WS_XL    = WS_XH + (size_t)NROWS * D * 2;
constexpr size_t WS_EHT   = WS_XL + (size_t)NROWS * D * 2;          // K*D bf16 (transposed)
constexpr size_t WS_ELT   = WS_EHT + (size_t)K * D * 2;

typedef unsigned int u32;
typedef unsigned short u16;
typedef unsigned long long u64;
typedef __attribute__((ext_vector_type(8))) short bf16x8;
typedef __attribute__((ext_vector_type(4))) float f32x4;
typedef __attribute__((ext_vector_type(4))) u32 u32x4;
typedef __attribute__((ext_vector_type(2))) u32 u32x2;

__device__ __forceinline__ u16 f2bf(float f) {
    u32 u = __float_as_uint(f);
    u32 r = (u + 0x7FFFu + ((u >> 16) & 1u)) >> 16;   // RN-even
    return (u16)r;
}
__device__ __forceinline__ float bf2f(u16 h) {
    return __uint_as_float((u32)h << 16);
}

__device__ __forceinline__ void gl_lds16(const void* g, void* l) {
    __builtin_amdgcn_global_load_lds(
        (const __attribute__((address_space(1))) u32*)g,
        (__attribute__((address_space(3))) u32*)l, 16, 0, 0);
}

// ---------------------------------------------------------------------------
// P1: split x into bf16 hi/lo (row-major, same layout as x)
__global__ void split_x_kernel(const float* __restrict__ x,
                               u16* __restrict__ xh, u16* __restrict__ xl) {
    size_t g = (size_t)blockIdx.x * blockDim.x + threadIdx.x;   // < NROWS*D/4
    float4 v = *(const float4*)&x[g * 4];
    u16 h0 = f2bf(v.x), h1 = f2bf(v.y), h2 = f2bf(v.z), h3 = f2bf(v.w);
    u16 l0 = f2bf(v.x - bf2f(h0)), l1 = f2bf(v.y - bf2f(h1));
    u16 l2 = f2bf(v.z - bf2f(h2)), l3 = f2bf(v.w - bf2f(h3));
    u32x2 hp, lp;
    hp.x = (u32)h0 | ((u32)h1 << 16); hp.y = (u32)h2 | ((u32)h3 << 16);
    lp.x = (u32)l0 | ((u32)l1 << 16); lp.y = (u32)l2 | ((u32)l3 << 16);
    ((u32x2*)xh)[g] = hp;
    ((u32x2*)xl)[g] = lp;
}

// P2: transpose + split embed (D,K) -> ehT/elT (K,D) bf16
__global__ void transpose_split_e(const float* __restrict__ embed,
                                  u16* __restrict__ ehT, u16* __restrict__ elT) {
    __shared__ float tile[64][68];
    const int kBase = blockIdx.x * 64;   // 128
    const int dBase = blockIdx.y * 64;   // 4
    const int t = threadIdx.x;           // 256
    {
        const int dl = t >> 2, q = t & 3;
        #pragma unroll
        for (int i = 0; i < 4; ++i) {
            int kk = q * 16 + i * 4;
            float4 v = *(const float4*)&embed[(size_t)(dBase + dl) * K + kBase + kk];
            *(float4*)&tile[dl][kk] = v;
        }
    }
    __syncthreads();
    const int kl = t >> 2, q = t & 3;
    u32 hp[8], lp[8];
    #pragma unroll
    for (int j = 0; j < 16; ++j) {
        float f = tile[q * 16 + j][kl];
        u16 hb = f2bf(f);
        u16 lb = f2bf(f - bf2f(hb));
        if (j & 1) { hp[j >> 1] |= (u32)hb << 16; lp[j >> 1] |= (u32)lb << 16; }
        else       { hp[j >> 1]  = hb;            lp[j >> 1]  = lb; }
    }
    size_t o = ((size_t)(kBase + kl) * D + dBase + q * 16) >> 1;   // uint index
    u32x4 a, b;
    a.x = hp[0]; a.y = hp[1]; a.z = hp[2]; a.w = hp[3];
    b.x = hp[4]; b.y = hp[5]; b.z = hp[6]; b.w = hp[7];
    *(u32x4*)&((u32*)ehT)[o]     = a;
    *(u32x4*)&((u32*)ehT)[o + 4] = b;
    a.x = lp[0]; a.y = lp[1]; a.z = lp[2]; a.w = lp[3];
    b.x = lp[4]; b.y = lp[5]; b.z = lp[6]; b.w = lp[7];
    *(u32x4*)&((u32*)elT)[o]     = a;
    *(u32x4*)&((u32*)elT)[o + 4] = b;
}

// P3: enorm[k] = sum_d embed[d,k]^2 (fp32, from original embed)
__global__ void enorm_kernel(const float* __restrict__ embed,
                             float* __restrict__ enorm) {
    int k = blockIdx.x * blockDim.x + threadIdx.x;
    float a0 = 0.f, a1 = 0.f, a2 = 0.f, a3 = 0.f;
    for (int d = 0; d < D; d += 4) {
        float e0 = embed[(size_t)(d + 0) * K + k];
        float e1 = embed[(size_t)(d + 1) * K + k];
        float e2 = embed[(size_t)(d + 2) * K + k];
        float e3 = embed[(size_t)(d + 3) * K + k];
        a0 = fmaf(e0, e0, a0); a1 = fmaf(e1, e1, a1);
        a2 = fmaf(e2, e2, a2); a3 = fmaf(e3, e3, a3);
    }
    enorm[k] = (a0 + a1) + (a2 + a3);
}

// P4: init EMA outputs with decay*old
__global__ void init_ema_kernel(const float* __restrict__ embed_avg,
                                const float* __restrict__ cluster_size,
                                float* __restrict__ nea_out,
                                float* __restrict__ ncs_out) {
    size_t i = (size_t)blockIdx.x * blockDim.x + threadIdx.x;
    nea_out[i] = DECAY * embed_avg[i];
    if (i < (size_t)K) ncs_out[i] = DECAY * cluster_size[i];
}

// P5: sum(cluster_size)
__global__ void cs_sum_kernel(const float* __restrict__ cluster_size,
                              float* __restrict__ nsum) {
    int i = blockIdx.x * blockDim.x + threadIdx.x;
    float v = cluster_size[i];
    #pragma unroll
    for (int off = 32; off > 0; off >>= 1) v += __shfl_down(v, off);
    __shared__ float wsum[4];
    if ((threadIdx.x & 63) == 0) wsum[threadIdx.x >> 6] = v;
    __syncthreads();
    if (threadIdx.x == 0)
        atomicAdd(nsum, wsum[0] + wsum[1] + wsum[2] + wsum[3]);
}

// ---------------------------------------------------------------------------
// K-MAIN: bf16x3 split MFMA distance GEMM + per-row argmin.
// score(r,k) = enorm[k] - 2*(xh.eh + xh.el + xl.eh)  (||x||^2 row-const dropped)
// 128x128 tile, BK=32, 4 waves (2x2 of 64x64), mfma_f32_16x16x32_bf16.
__global__ __launch_bounds__(256) void dist_argmin_mfma(
        const u16* __restrict__ xh, const u16* __restrict__ xl,
        const u16* __restrict__ ehT, const u16* __restrict__ elT,
        const float* __restrict__ enorm,
        u64* __restrict__ keys) {
    __shared__ u16 ah[128 * 32];
    __shared__ u16 al[128 * 32];
    __shared__ u16 bh[128 * 32];
    __shared__ u16 bl[128 * 32];

    const int tid  = threadIdx.x;
    const int lane = tid & 63;
    const int wave = tid >> 6;
    const int wm = wave >> 1, wn = wave & 1;
    const int r = lane & 15, g = lane >> 4;
    const int rowBase = blockIdx.y * 128;
    const int colBase = blockIdx.x * 128;

    f32x4 acc[4][4];
    #pragma unroll
    for (int i = 0; i < 4; ++i)
        #pragma unroll
        for (int j = 0; j < 4; ++j) acc[i][j] = (f32x4)0.f;

    // staging: thread covers LDS row tid/4 (and +64), cols (tid%4)*8..+8
    const int srow = tid >> 2;
    const int scol = (tid & 3) * 8;
    const size_t abase = (size_t)(rowBase + srow) * D + scol;
    const size_t bbase = (size_t)(colBase + srow) * D + scol;
    u16* ah0 = &ah[tid * 8]; u16* ah1 = &ah[tid * 8 + 2048];
    u16* al0 = &al[tid * 8]; u16* al1 = &al[tid * 8 + 2048];
    u16* bh0 = &bh[tid * 8]; u16* bh1 = &bh[tid * 8 + 2048];
    u16* bl0 = &bl[tid * 8]; u16* bl1 = &bl[tid * 8 + 2048];

    for (int ks = 0; ks < 8; ++ks) {
        const int dofs = ks * 32;
        gl_lds16(&xh[abase + dofs], ah0);
        gl_lds16(&xh[abase + (size_t)64 * D + dofs], ah1);
        gl_lds16(&xl[abase + dofs], al0);
        gl_lds16(&xl[abase + (size_t)64 * D + dofs], al1);
        gl_lds16(&ehT[bbase + dofs], bh0);
        gl_lds16(&ehT[bbase + (size_t)64 * D + dofs], bh1);
        gl_lds16(&elT[bbase + dofs], bl0);
        gl_lds16(&elT[bbase + (size_t)64 * D + dofs], bl1);
        __syncthreads();   // drains vmcnt -> LDS tiles ready

        bf16x8 fah[4], fal[4], fbh[4], fbl[4];
        #pragma unroll
        for (int i = 0; i < 4; ++i) {
            fah[i] = *(const bf16x8*)&ah[(wm * 64 + i * 16 + r) * 32 + g * 8];
            fal[i] = *(const bf16x8*)&al[(wm * 64 + i * 16 + r) * 32 + g * 8];
            fbh[i] = *(const bf16x8*)&bh[(wn * 64 + i * 16 + r) * 32 + g * 8];
            fbl[i] = *(const bf16x8*)&bl[(wn * 64 + i * 16 + r) * 32 + g * 8];
        }
        #pragma unroll
        for (int i = 0; i < 4; ++i)
            #pragma unroll
            for (int j = 0; j < 4; ++j) {
                acc[i][j] = __builtin_amdgcn_mfma_f32_16x16x32_bf16(fah[i], fbh[j], acc[i][j], 0, 0, 0);
                acc[i][j] = __builtin_amdgcn_mfma_f32_16x16x32_bf16(fah[i], fbl[j], acc[i][j], 0, 0, 0);
                acc[i][j] = __builtin_amdgcn_mfma_f32_16x16x32_bf16(fal[i], fbh[j], acc[i][j], 0, 0, 0);
            }
        __syncthreads();   // safe to overwrite LDS next iter
    }

    // epilogue: C/D layout col=lane&15, row=(lane>>4)*4+p (verified m89/m91)
    float en[4];
    #pragma unroll
    for (int j = 0; j < 4; ++j) en[j] = enorm[colBase + wn * 64 + j * 16 + r];

    #pragma unroll
    for (int i = 0; i < 4; ++i) {
        #pragma unroll
        for (int p = 0; p < 4; ++p) {
            float best = __builtin_inff();
            int bk = 0;
            #pragma unroll
            for (int j = 0; j < 4; ++j) {
                float s = fmaf(-2.f, acc[i][j][p], en[j]);
                int c = colBase + wn * 64 + j * 16 + r;
                if (s < best) { best = s; bk = c; }
            }
            u32 u = __float_as_uint(best);
            u ^= (u >> 31) ? 0xFFFFFFFFu : 0x80000000u;   // monotonic float->uint
            u64 key = ((u64)u << 32) | (u32)bk;
            #pragma unroll
            for (int m = 1; m < 16; m <<= 1) {
                u64 o = __shfl_xor(key, m);
                key = o < key ? o : key;
            }
            if (r == 0)
                atomicMin(&keys[rowBase + wm * 64 + i * 16 + g * 4 + p], key);
        }
    }
}

// ---------------------------------------------------------------------------
// K4: EMA scatter. One block per row.
__global__ void scatter_kernel(const float* __restrict__ x,
                               const u64* __restrict__ keys,
                               float* __restrict__ nea_out,
                               float* __restrict__ ncs_out) {
    int r = blockIdx.x;
    int d = threadIdx.x;
    u32 k = (u32)keys[r];
    atomicAdd(&nea_out[(size_t)d * K + k], OMD * x[(size_t)r * D + d]);
    if (d == 0) atomicAdd(&ncs_out[k], OMD);
}

// K5: quantize gather (coalesced via ehT/elT hi+lo reconstruction) + loss
__global__ void quantize_loss_kernel(const float* __restrict__ x,
                                     const u16* __restrict__ ehT,
                                     const u16* __restrict__ elT,
                                     const u64* __restrict__ keys,
                                     float* __restrict__ q_out,
                                     float* __restrict__ loss_out) {
    float lsum = 0.f;
    const size_t total = (size_t)NROWS * D / 4;
    for (size_t g = (size_t)blockIdx.x * blockDim.x + threadIdx.x; g < total;
         g += (size_t)gridDim.x * blockDim.x) {
        int rrow = (int)(g >> 6);           // D/4 = 64 groups per row
        int c4   = (int)(g & 63) * 4;
        u32 k = (u32)keys[rrow];
        size_t uo = ((size_t)k * D + c4) >> 1;
        u32x2 hp = *(const u32x2*)&((const u32*)ehT)[uo];
        u32x2 lp = *(const u32x2*)&((const u32*)elT)[uo];
        float4 xv = *(const float4*)&x[g * 4];
        float q0 = __uint_as_float(hp.x << 16)          + __uint_as_float(lp.x << 16);
        float q1 = __uint_as_float(hp.x & 0xFFFF0000u)  + __uint_as_float(lp.x & 0xFFFF0000u);
        float q2 = __uint_as_float(hp.y << 16)          + __uint_as_float(lp.y << 16);
        float q3 = __uint_as_float(hp.y & 0xFFFF0000u)  + __uint_as_float(lp.y & 0xFFFF0000u);
        float4 qv = make_float4(q0, q1, q2, q3);
        *(float4*)&q_out[g * 4] = qv;
        float d0 = q0 - xv.x, d1 = q1 - xv.y, d2 = q2 - xv.z, d3 = q3 - xv.w;
        lsum = fmaf(d0, d0, lsum); lsum = fmaf(d1, d1, lsum);
        lsum = fmaf(d2, d2, lsum); lsum = fmaf(d3, d3, lsum);
    }
    #pragma unroll
    for (int off = 32; off > 0; off >>= 1) lsum += __shfl_down(lsum, off);
    __shared__ float wsum[4];
    if ((threadIdx.x & 63) == 0) wsum[threadIdx.x >> 6] = lsum;
    __syncthreads();
    if (threadIdx.x == 0) {
        float s = wsum[0] + wsum[1] + wsum[2] + wsum[3];
        atomicAdd(loss_out, s * (1.0f / ((float)NROWS * (float)D)));
    }
}

// K6: new_embed = new_embed_avg / cs(k)
__global__ void new_embed_kernel(const float* __restrict__ nea_out,
                                 const float* __restrict__ ncs_out,
                                 const float* __restrict__ nsum,
                                 float* __restrict__ ne_out) {
    size_t i = (size_t)blockIdx.x * blockDim.x + threadIdx.x;
    int k = (int)(i & (size_t)(K - 1));
    float n  = DECAY * (*nsum) + OMD * (float)NROWS;
    float cs = (ncs_out[k] + EPSF) / (n + (float)K * EPSF) * n;
    ne_out[i] = nea_out[i] / cs;
}

// ---------------------------------------------------------------------------
extern "C" void kernel_launch(void* const* d_in, const int* in_sizes, int n_in,
                              void* d_out, int out_size, void* d_ws, size_t ws_size,
                              hipStream_t stream) {
    (void)in_sizes; (void)n_in; (void)out_size; (void)ws_size;
    const float* x            = (const float*)d_in[0];
    const float* embed        = (const float*)d_in[1];
    const float* cluster_size = (const float*)d_in[2];
    const float* embed_avg    = (const float*)d_in[3];
    float* out = (float*)d_out;

    char* ws = (char*)d_ws;
    u64*   keys  = (u64*)(ws + WS_KEYS);
    float* enorm = (float*)(ws + WS_ENORM);
    float* nsum  = (float*)(ws + WS_NSUM);
    u16*   xh    = (u16*)(ws + WS_XH);
    u16*   xl    = (u16*)(ws + WS_XL);
    u16*   ehT   = (u16*)(ws + WS_EHT);
    u16*   elT   = (u16*)(ws + WS_ELT);

    float* q_out    = out + OUT_Q;
    float* loss_out = out + OUT_LOSS;
    float* ne_out   = out + OUT_NE;
    float* ncs_out  = out + OUT_NCS;
    float* nea_out  = out + OUT_NEA;

    hipMemsetAsync(keys, 0xFF, (size_t)NROWS * 8, stream);
    hipMemsetAsync(nsum, 0, 4, stream);
    hipMemsetAsync(loss_out, 0, 4, stream);

    split_x_kernel<<<dim3(NROWS * D / 4 / 256), dim3(256), 0, stream>>>(x, xh, xl);
    transpose_split_e<<<dim3(K / 64, D / 64), dim3(256), 0, stream>>>(embed, ehT, elT);
    enorm_kernel<<<dim3(K / 256), dim3(256), 0, stream>>>(embed, enorm);
    init_ema_kernel<<<dim3((D * K) / 256), dim3(256), 0, stream>>>(
        embed_avg, cluster_size, nea_out, ncs_out);
    cs_sum_kernel<<<dim3(K / 256), dim3(256), 0, stream>>>(cluster_size, nsum);

    dist_argmin_mfma<<<dim3(K / 128, NROWS / 128), dim3(256), 0, stream>>>(
        xh, xl, ehT, elT, enorm, keys);

    scatter_kernel<<<dim3(NROWS), dim3(256), 0, stream>>>(x, keys, nea_out, ncs_out);
    quantize_loss_kernel<<<dim3(512), dim3(256), 0, stream>>>(
        x, ehT, elT, keys, q_out, loss_out);
    new_embed_kernel<<<dim3((D * K) / 256), dim3(256), 0, stream>>>(
        nea_out, ncs_out, nsum, ne_out);
}

// Round 3
// 419.150 us; speedup vs baseline: 2.5674x; 1.3203x over previous
//
#include <hip/hip_runtime.h>

// Problem constants (B=16,H=32,W=32,D=256,K=8192)
constexpr int NROWS = 16384;   // B*H*W
constexpr int D     = 256;
constexpr int K     = 8192;

constexpr float DECAY = 0.99f;
constexpr float OMD   = 0.01f;   // 1 - DECAY
constexpr float EPSF  = 1e-5f;

// Output layout (flat fp32, concatenated in return order)
constexpr size_t OUT_Q    = 0;                          // quantize_st  : NROWS*D
constexpr size_t OUT_LOSS = (size_t)NROWS * D;          // latent_loss  : 1
constexpr size_t OUT_NE   = OUT_LOSS + 1;               // new_embed    : D*K
constexpr size_t OUT_NCS  = OUT_NE + (size_t)D * K;     // new_cluster  : K
constexpr size_t OUT_NEA  = OUT_NCS + K;                // new_embed_avg: D*K

// Workspace byte offsets
constexpr size_t WS_KEYS  = 0;                              // NROWS u64   (128 KB)
constexpr size_t WS_ENORM = WS_KEYS + (size_t)NROWS * 8;    // K f32       (32 KB)
constexpr size_t WS_NSUM  = WS_ENORM + (size_t)K * 4;       // 1 f32
constexpr size_t WS_XH    = ((WS_NSUM + 4096) / 4096) * 4096;       // NROWS*D bf16 (8MB)
constexpr size_t WS_XL    = WS_XH + (size_t)NROWS * D * 2;          // 8MB
constexpr size_t WS_EHT   = WS_XL + (size_t)NROWS * D * 2;          // K*D bf16 (4MB)
constexpr size_t WS_ELT   = WS_EHT + (size_t)K * D * 2;             // 4MB
// acc_t[K][D] f32 (8MB) aliases WS_XH after the main kernel (xh dead by then)

typedef unsigned int u32;
typedef unsigned short u16;
typedef unsigned long long u64;
typedef __attribute__((ext_vector_type(8))) short bf16x8;
typedef __attribute__((ext_vector_type(4))) float f32x4;
typedef __attribute__((ext_vector_type(4))) u32 u32x4;
typedef __attribute__((ext_vector_type(2))) u32 u32x2;

__device__ __forceinline__ u16 f2bf(float f) {
    u32 u = __float_as_uint(f);
    u32 r = (u + 0x7FFFu + ((u >> 16) & 1u)) >> 16;   // RN-even
    return (u16)r;
}
__device__ __forceinline__ float bf2f(u16 h) {
    return __uint_as_float((u32)h << 16);
}

__device__ __forceinline__ void gl_lds16(const void* g, void* l) {
    __builtin_amdgcn_global_load_lds(
        (const __attribute__((address_space(1))) u32*)g,
        (__attribute__((address_space(3))) u32*)l, 16, 0, 0);
}

// ---------------------------------------------------------------------------
// P1: split x into bf16 hi/lo (row-major, same layout as x)
__global__ void split_x_kernel(const float* __restrict__ x,
                               u16* __restrict__ xh, u16* __restrict__ xl) {
    size_t g = (size_t)blockIdx.x * blockDim.x + threadIdx.x;   // < NROWS*D/4
    float4 v = *(const float4*)&x[g * 4];
    u16 h0 = f2bf(v.x), h1 = f2bf(v.y), h2 = f2bf(v.z), h3 = f2bf(v.w);
    u16 l0 = f2bf(v.x - bf2f(h0)), l1 = f2bf(v.y - bf2f(h1));
    u16 l2 = f2bf(v.z - bf2f(h2)), l3 = f2bf(v.w - bf2f(h3));
    u32x2 hp, lp;
    hp.x = (u32)h0 | ((u32)h1 << 16); hp.y = (u32)h2 | ((u32)h3 << 16);
    lp.x = (u32)l0 | ((u32)l1 << 16); lp.y = (u32)l2 | ((u32)l3 << 16);
    ((u32x2*)xh)[g] = hp;
    ((u32x2*)xl)[g] = lp;
}

// P2: transpose + split embed (D,K) -> ehT/elT (K,D) bf16
__global__ void transpose_split_e(const float* __restrict__ embed,
                                  u16* __restrict__ ehT, u16* __restrict__ elT) {
    __shared__ float tile[64][68];
    const int kBase = blockIdx.x * 64;   // 128
    const int dBase = blockIdx.y * 64;   // 4
    const int t = threadIdx.x;           // 256
    {
        const int dl = t >> 2, q = t & 3;
        #pragma unroll
        for (int i = 0; i < 4; ++i) {
            int kk = q * 16 + i * 4;
            float4 v = *(const float4*)&embed[(size_t)(dBase + dl) * K + kBase + kk];
            tile[dl][kk + 0] = v.x; tile[dl][kk + 1] = v.y;
            tile[dl][kk + 2] = v.z; tile[dl][kk + 3] = v.w;
        }
    }
    __syncthreads();
    const int kl = t >> 2, q = t & 3;
    u32 hp[8], lp[8];
    #pragma unroll
    for (int j = 0; j < 16; ++j) {
        float f = tile[q * 16 + j][kl];
        u16 hb = f2bf(f);
        u16 lb = f2bf(f - bf2f(hb));
        if (j & 1) { hp[j >> 1] |= (u32)hb << 16; lp[j >> 1] |= (u32)lb << 16; }
        else       { hp[j >> 1]  = hb;            lp[j >> 1]  = lb; }
    }
    size_t o = ((size_t)(kBase + kl) * D + dBase + q * 16) >> 1;   // uint index
    u32x4 a, b;
    a.x = hp[0]; a.y = hp[1]; a.z = hp[2]; a.w = hp[3];
    b.x = hp[4]; b.y = hp[5]; b.z = hp[6]; b.w = hp[7];
    *(u32x4*)&((u32*)ehT)[o]     = a;
    *(u32x4*)&((u32*)ehT)[o + 4] = b;
    a.x = lp[0]; a.y = lp[1]; a.z = lp[2]; a.w = lp[3];
    b.x = lp[4]; b.y = lp[5]; b.z = lp[6]; b.w = lp[7];
    *(u32x4*)&((u32*)elT)[o]     = a;
    *(u32x4*)&((u32*)elT)[o + 4] = b;
}

// P3: enorm[k] = sum_d embed[d,k]^2 (fp32, from original embed)
__global__ void enorm_kernel(const float* __restrict__ embed,
                             float* __restrict__ enorm) {
    int k = blockIdx.x * blockDim.x + threadIdx.x;
    float a0 = 0.f, a1 = 0.f, a2 = 0.f, a3 = 0.f;
    for (int d = 0; d < D; d += 4) {
        float e0 = embed[(size_t)(d + 0) * K + k];
        float e1 = embed[(size_t)(d + 1) * K + k];
        float e2 = embed[(size_t)(d + 2) * K + k];
        float e3 = embed[(size_t)(d + 3) * K + k];
        a0 = fmaf(e0, e0, a0); a1 = fmaf(e1, e1, a1);
        a2 = fmaf(e2, e2, a2); a3 = fmaf(e3, e3, a3);
    }
    enorm[k] = (a0 + a1) + (a2 + a3);
}

// P4: ncs_out = 0.99*cluster_size; nsum = sum(cluster_size)
__global__ void cs_init_sum_kernel(const float* __restrict__ cluster_size,
                                   float* __restrict__ ncs_out,
                                   float* __restrict__ nsum) {
    int i = blockIdx.x * blockDim.x + threadIdx.x;   // K threads
    float v = cluster_size[i];
    ncs_out[i] = DECAY * v;
    #pragma unroll
    for (int off = 32; off > 0; off >>= 1) v += __shfl_down(v, off);
    __shared__ float wsum[4];
    if ((threadIdx.x & 63) == 0) wsum[threadIdx.x >> 6] = v;
    __syncthreads();
    if (threadIdx.x == 0)
        atomicAdd(nsum, wsum[0] + wsum[1] + wsum[2] + wsum[3]);
}

// ---------------------------------------------------------------------------
// K-MAIN: bf16x3 split MFMA distance GEMM + per-row argmin.
// score(r,k) = enorm[k] - 2*(xh.eh + xh.el + xl.eh)  (||x||^2 row-const dropped)
// 128x128 tile, BK=32, 4 waves (2x2 of 64x64), mfma_f32_16x16x32_bf16.
// v3: double-buffered LDS (one barrier/K-step, loads in flight across the
// MFMA phase) + XOR bank-swizzle (applied to the GLOBAL source d-offset,
// inverse applied on the LDS read side) + setprio around the MFMA cluster.
__global__ __launch_bounds__(256) void dist_argmin_mfma(
        const u16* __restrict__ xh, const u16* __restrict__ xl,
        const u16* __restrict__ ehT, const u16* __restrict__ elT,
        const float* __restrict__ enorm,
        u64* __restrict__ keys) {
    // [buf][op: ah,al,bh,bl][128 rows * 32 k]  = 64 KB total
    __shared__ u16 smem[2][4][128 * 32];

    const int tid  = threadIdx.x;
    const int lane = tid & 63;
    const int wave = tid >> 6;
    const int wm = wave >> 1, wn = wave & 1;
    const int r = lane & 15, g = lane >> 4;
    const int rowBase = blockIdx.y * 128;
    const int colBase = blockIdx.x * 128;

    f32x4 acc[4][4];
    #pragma unroll
    for (int i = 0; i < 4; ++i)
        #pragma unroll
        for (int j = 0; j < 4; ++j) acc[i][j] = (f32x4)0.f;

    // Staging: thread covers LDS row tid/4 (and +64). The 16B k-chunk slot is
    // XOR-swizzled with (row>>1)&3, applied to the GLOBAL source address
    // (gl_lds dest must stay linear: wave base + lane*16).
    const int srow = tid >> 2;
    const int sd   = ((tid & 3) ^ ((tid >> 3) & 3)) * 8;   // swizzled d-chunk (u16)
    const size_t abase = (size_t)(rowBase + srow) * D + sd;
    const size_t bbase = (size_t)(colBase + srow) * D + sd;
    // Read side: same XOR on the k-chunk; (row>>1)&3 == (r>>1)&3 for our rows.
    const int kx = (g ^ ((r >> 1) & 3)) * 8;                // u16 offset in row

    #define STAGE(buf, ks)                                                        \
        do {                                                                      \
            const int dofs_ = (ks) * 32;                                          \
            gl_lds16(&xh [abase + dofs_],                 &smem[buf][0][tid * 8]);        \
            gl_lds16(&xh [abase + (size_t)64 * D + dofs_],&smem[buf][0][tid * 8 + 2048]); \
            gl_lds16(&xl [abase + dofs_],                 &smem[buf][1][tid * 8]);        \
            gl_lds16(&xl [abase + (size_t)64 * D + dofs_],&smem[buf][1][tid * 8 + 2048]); \
            gl_lds16(&ehT[bbase + dofs_],                 &smem[buf][2][tid * 8]);        \
            gl_lds16(&ehT[bbase + (size_t)64 * D + dofs_],&smem[buf][2][tid * 8 + 2048]); \
            gl_lds16(&elT[bbase + dofs_],                 &smem[buf][3][tid * 8]);        \
            gl_lds16(&elT[bbase + (size_t)64 * D + dofs_],&smem[buf][3][tid * 8 + 2048]); \
        } while (0)

    STAGE(0, 0);
    __syncthreads();   // drain prologue loads

    #pragma unroll
    for (int ks = 0; ks < 8; ++ks) {
        const int cur = ks & 1;
        if (ks < 7) STAGE(cur ^ 1, ks + 1);   // next tile in flight across MFMAs

        bf16x8 fah[4], fal[4], fbh[4], fbl[4];
        #pragma unroll
        for (int i = 0; i < 4; ++i) {
            fah[i] = *(const bf16x8*)&smem[cur][0][(wm * 64 + i * 16 + r) * 32 + kx];
            fal[i] = *(const bf16x8*)&smem[cur][1][(wm * 64 + i * 16 + r) * 32 + kx];
            fbh[i] = *(const bf16x8*)&smem[cur][2][(wn * 64 + i * 16 + r) * 32 + kx];
            fbl[i] = *(const bf16x8*)&smem[cur][3][(wn * 64 + i * 16 + r) * 32 + kx];
        }
        __builtin_amdgcn_s_setprio(1);
        #pragma unroll
        for (int i = 0; i < 4; ++i)
            #pragma unroll
            for (int j = 0; j < 4; ++j) {
                acc[i][j] = __builtin_amdgcn_mfma_f32_16x16x32_bf16(fah[i], fbh[j], acc[i][j], 0, 0, 0);
                acc[i][j] = __builtin_amdgcn_mfma_f32_16x16x32_bf16(fah[i], fbl[j], acc[i][j], 0, 0, 0);
                acc[i][j] = __builtin_amdgcn_mfma_f32_16x16x32_bf16(fal[i], fbh[j], acc[i][j], 0, 0, 0);
            }
        __builtin_amdgcn_s_setprio(0);
        if (ks < 7) __syncthreads();   // vmcnt(0)+lgkm drain + barrier, once/step
    }
    #undef STAGE

    // epilogue: C/D layout col=lane&15, row=(lane>>4)*4+p (verified m89/m91)
    float en[4];
    #pragma unroll
    for (int j = 0; j < 4; ++j) en[j] = enorm[colBase + wn * 64 + j * 16 + r];

    #pragma unroll
    for (int i = 0; i < 4; ++i) {
        #pragma unroll
        for (int p = 0; p < 4; ++p) {
            float best = __builtin_inff();
            int bk = 0;
            #pragma unroll
            for (int j = 0; j < 4; ++j) {
                float s = fmaf(-2.f, acc[i][j][p], en[j]);
                int c = colBase + wn * 64 + j * 16 + r;
                if (s < best) { best = s; bk = c; }
            }
            u32 u = __float_as_uint(best);
            u ^= (u >> 31) ? 0xFFFFFFFFu : 0x80000000u;   // monotonic float->uint
            u64 key = ((u64)u << 32) | (u32)bk;
            #pragma unroll
            for (int m = 1; m < 16; m <<= 1) {
                u64 o = __shfl_xor(key, m);
                key = o < key ? o : key;
            }
            if (r == 0)
                atomicMin(&keys[rowBase + wm * 64 + i * 16 + g * 4 + p], key);
        }
    }
}

// ---------------------------------------------------------------------------
// K4: EMA scatter into TRANSPOSED accumulator acc_t[K][D] — contiguous,
// float4-coalesced atomics (1 wave per row) instead of 256 stride-K lines.
__global__ void scatter_kernel(const float* __restrict__ x,
                               const u64* __restrict__ keys,
                               float* __restrict__ acc_t,
                               float* __restrict__ ncs_out) {
    int r    = blockIdx.x * 4 + (threadIdx.x >> 6);
    int lane = threadIdx.x & 63;
    u32 k = (u32)keys[r];
    float4 v = *(const float4*)&x[(size_t)r * D + lane * 4];
    float* dst = &acc_t[(size_t)k * D + lane * 4];
    atomicAdd(dst + 0, v.x);
    atomicAdd(dst + 1, v.y);
    atomicAdd(dst + 2, v.z);
    atomicAdd(dst + 3, v.w);
    if (lane == 0) atomicAdd(&ncs_out[k], OMD);
}

// K5: quantize gather (coalesced via ehT/elT hi+lo reconstruction) + loss
__global__ void quantize_loss_kernel(const float* __restrict__ x,
                                     const u16* __restrict__ ehT,
                                     const u16* __restrict__ elT,
                                     const u64* __restrict__ keys,
                                     float* __restrict__ q_out,
                                     float* __restrict__ loss_out) {
    float lsum = 0.f;
    const size_t total = (size_t)NROWS * D / 4;
    for (size_t g = (size_t)blockIdx.x * blockDim.x + threadIdx.x; g < total;
         g += (size_t)gridDim.x * blockDim.x) {
        int rrow = (int)(g >> 6);           // D/4 = 64 groups per row
        int c4   = (int)(g & 63) * 4;
        u32 k = (u32)keys[rrow];
        size_t uo = ((size_t)k * D + c4) >> 1;
        u32x2 hp = *(const u32x2*)&((const u32*)ehT)[uo];
        u32x2 lp = *(const u32x2*)&((const u32*)elT)[uo];
        float4 xv = *(const float4*)&x[g * 4];
        float q0 = __uint_as_float(hp.x << 16)          + __uint_as_float(lp.x << 16);
        float q1 = __uint_as_float(hp.x & 0xFFFF0000u)  + __uint_as_float(lp.x & 0xFFFF0000u);
        float q2 = __uint_as_float(hp.y << 16)          + __uint_as_float(lp.y << 16);
        float q3 = __uint_as_float(hp.y & 0xFFFF0000u)  + __uint_as_float(lp.y & 0xFFFF0000u);
        float4 qv = make_float4(q0, q1, q2, q3);
        *(float4*)&q_out[g * 4] = qv;
        float d0 = q0 - xv.x, d1 = q1 - xv.y, d2 = q2 - xv.z, d3 = q3 - xv.w;
        lsum = fmaf(d0, d0, lsum); lsum = fmaf(d1, d1, lsum);
        lsum = fmaf(d2, d2, lsum); lsum = fmaf(d3, d3, lsum);
    }
    #pragma unroll
    for (int off = 32; off > 0; off >>= 1) lsum += __shfl_down(lsum, off);
    __shared__ float wsum[4];
    if ((threadIdx.x & 63) == 0) wsum[threadIdx.x >> 6] = lsum;
    __syncthreads();
    if (threadIdx.x == 0) {
        float s = wsum[0] + wsum[1] + wsum[2] + wsum[3];
        atomicAdd(loss_out, s * (1.0f / ((float)NROWS * (float)D)));
    }
}

// K6: fused finalize — transpose acc_t[K][D] -> nea_out[D][K] combined with
// EMA (0.99*embed_avg + 0.01*acc) AND new_embed = nea/cs in one pass.
__global__ void ema_finalize_kernel(const float* __restrict__ embed_avg,
                                    const float* __restrict__ acc_t,
                                    const float* __restrict__ ncs_out,
                                    const float* __restrict__ nsum,
                                    float* __restrict__ nea_out,
                                    float* __restrict__ ne_out) {
    __shared__ float tile[64][68];   // [k][d]
    const int kBase = blockIdx.x * 64;   // K/64 = 128
    const int dBase = blockIdx.y * 64;   // D/64 = 4
    const int t = threadIdx.x;
    {
        const int kl = t >> 2, q = t & 3;
        #pragma unroll
        for (int i = 0; i < 4; ++i) {
            int dd = q * 16 + i * 4;
            float4 v = *(const float4*)&acc_t[(size_t)(kBase + kl) * D + dBase + dd];
            tile[kl][dd + 0] = v.x; tile[kl][dd + 1] = v.y;
            tile[kl][dd + 2] = v.z; tile[kl][dd + 3] = v.w;
        }
    }
    __syncthreads();
    const int dl = t >> 2, q = t & 3;
    const float n = DECAY * (*nsum) + OMD * (float)NROWS;
    const float inv_na = 1.0f / (n + (float)K * EPSF);
    #pragma unroll
    for (int i = 0; i < 4; ++i) {
        int kk = q * 16 + i * 4;
        size_t o = (size_t)(dBase + dl) * K + kBase + kk;
        float4 ea = *(const float4*)&embed_avg[o];
        float4 nea, ne;
        #pragma unroll
        for (int c = 0; c < 4; ++c) {
            float v  = DECAY * ((const float*)&ea)[c] + OMD * tile[kk + c][dl];
            float cs = (ncs_out[kBase + kk + c] + EPSF) * inv_na * n;
            ((float*)&nea)[c] = v;
            ((float*)&ne)[c]  = v / cs;
        }
        *(float4*)&nea_out[o] = nea;
        *(float4*)&ne_out[o]  = ne;
    }
}

// ---------------------------------------------------------------------------
extern "C" void kernel_launch(void* const* d_in, const int* in_sizes, int n_in,
                              void* d_out, int out_size, void* d_ws, size_t ws_size,
                              hipStream_t stream) {
    (void)in_sizes; (void)n_in; (void)out_size; (void)ws_size;
    const float* x            = (const float*)d_in[0];
    const float* embed        = (const float*)d_in[1];
    const float* cluster_size = (const float*)d_in[2];
    const float* embed_avg    = (const float*)d_in[3];
    float* out = (float*)d_out;

    char* ws = (char*)d_ws;
    u64*   keys  = (u64*)(ws + WS_KEYS);
    float* enorm = (float*)(ws + WS_ENORM);
    float* nsum  = (float*)(ws + WS_NSUM);
    u16*   xh    = (u16*)(ws + WS_XH);
    u16*   xl    = (u16*)(ws + WS_XL);
    u16*   ehT   = (u16*)(ws + WS_EHT);
    u16*   elT   = (u16*)(ws + WS_ELT);
    float* acc_t = (float*)(ws + WS_XH);   // aliases xh: dead after main kernel

    float* q_out    = out + OUT_Q;
    float* loss_out = out + OUT_LOSS;
    float* ne_out   = out + OUT_NE;
    float* ncs_out  = out + OUT_NCS;
    float* nea_out  = out + OUT_NEA;

    hipMemsetAsync(keys, 0xFF, (size_t)NROWS * 8, stream);
    hipMemsetAsync(nsum, 0, 4, stream);
    hipMemsetAsync(loss_out, 0, 4, stream);

    split_x_kernel<<<dim3(NROWS * D / 4 / 256), dim3(256), 0, stream>>>(x, xh, xl);
    transpose_split_e<<<dim3(K / 64, D / 64), dim3(256), 0, stream>>>(embed, ehT, elT);
    enorm_kernel<<<dim3(K / 256), dim3(256), 0, stream>>>(embed, enorm);
    cs_init_sum_kernel<<<dim3(K / 256), dim3(256), 0, stream>>>(
        cluster_size, ncs_out, nsum);

    dist_argmin_mfma<<<dim3(K / 128, NROWS / 128), dim3(256), 0, stream>>>(
        xh, xl, ehT, elT, enorm, keys);

    // xh is dead now; reuse it as the transposed EMA accumulator
    hipMemsetAsync(acc_t, 0, (size_t)K * D * 4, stream);
    scatter_kernel<<<dim3(NROWS / 4), dim3(256), 0, stream>>>(
        x, keys, acc_t, ncs_out);
    quantize_loss_kernel<<<dim3(512), dim3(256), 0, stream>>>(
        x, ehT, elT, keys, q_out, loss_out);
    ema_finalize_kernel<<<dim3(K / 64, D / 64), dim3(256), 0, stream>>>(
        embed_avg, acc_t, ncs_out, nsum, nea_out, ne_out);
}